// Round 7
// baseline (221.872 us; speedup 1.0000x reference)
//
#include <hip/hip_runtime.h>
#include <hip/hip_bf16.h>

#define DIM 256
#define HEADS 8
#define DH 32
#define AGENT 6
#define WIN 7
#define NTOK 294              // AGENT*WIN*WIN
#define BWIN 128              // B*X*Y = 2*8*8
#define SCALE 0.17677669529663687f  // 32^-0.5
#define LOG2E 1.4426950408889634f
#define TP 19                 // 16-row tiles covering 294 (padded to 304)
#define QSTR 40               // attn Qs/Ks LDS row stride
#define PSTR 320              // attn Vt LDS row stride: 640B = 5*128B (row 128B-aligned)

typedef __hip_bfloat16 bf16;
typedef __attribute__((ext_vector_type(8))) short s16x8;
typedef __attribute__((ext_vector_type(4))) float f32x4;
typedef __attribute__((ext_vector_type(4))) unsigned int u32x4;

#if __has_builtin(__builtin_amdgcn_exp2f)
#define EXP2(x) __builtin_amdgcn_exp2f(x)
#else
#define EXP2(x) exp2f(x)
#endif

__device__ __forceinline__ float bfv(unsigned short u){ return __uint_as_float(((unsigned int)u) << 16); }
__device__ __forceinline__ unsigned short f2bu(float f){
    bf16 b = __float2bfloat16(f); return *reinterpret_cast<unsigned short*>(&b);
}
__device__ __forceinline__ float rdf(const void* p, size_t idx, int isf32) {
    return isf32 ? ((const float*)p)[idx] : bfv(((const unsigned short*)p)[idx]);
}

// Vt byte-address swizzle: row d (128B-aligned, 640B), XOR key permutes 16B slots
// within each 128B block; bijective per row.
__device__ __forceinline__ int vtswz(int d, int cByte) {
    return (d * (PSTR * 2) + cByte) ^ (((d >> 1) & 7) << 4);
}

// async global->LDS, 16B per lane. LDS dest = uniform base + lane*16 (linear).
__device__ __forceinline__ void gll16(const void* gp, void* lp) {
    __builtin_amdgcn_global_load_lds(
        (const __attribute__((address_space(1))) unsigned int*)gp,
        (__attribute__((address_space(3))) unsigned int*)lp, 16, 0, 0);
}

// inline dtype detect: flag=1 -> f32 inputs, flag=0 -> bf16. Pure function of x.
__device__ __forceinline__ int detect_flag(const unsigned short* __restrict__ xraw,
                                           int* sflag, int nthreads) {
    if (threadIdx.x == 0) *sflag = 0;
    __syncthreads();
    int bad = 0;
    for (int i = threadIdx.x; i < 8192; i += nthreads) {
        float v = bfv(xraw[i]);
        if (!(fabsf(v) <= 1e10f)) bad = 1;
    }
    if (bad) atomicOr(sflag, 1);
    __syncthreads();
    return *sflag;
}

// ---------- prep: inline detect + W materialize (always bf16) + f32 bias build ----------
__global__ __launch_bounds__(256) void prep_kernel(
    const unsigned short* __restrict__ xraw,
    const void* __restrict__ wq, const void* __restrict__ wo, const void* __restrict__ bt,
    unsigned short* __restrict__ Wq, unsigned short* __restrict__ Wo,
    float* __restrict__ biasB) {
    __shared__ int sflag;
    const int isf32 = detect_flag(xraw, &sflag, 256);
    const int bid = blockIdx.x;
    if (bid < 722) {
        int idx = bid * 256 + threadIdx.x;
        int lane = idx & 63; int t = idx >> 6;
        int jt = t % TP; t /= TP; int it = t % TP; int h = t / TP;
        int i = it * 16 + (lane & 15);
        int g = lane >> 4;
        f32x4 v;
        #pragma unroll
        for (int r = 0; r < 4; r++) {
            int j = jt * 16 + g * 4 + r;
            float val = 0.f;
            if (i < NTOK && j < NTOK) {
                int li = i / 49, ri = i - li * 49, w1i = ri / 7, w2i = ri - w1i * 7;
                int lj = j / 49, rj = j - lj * 49, w1j = rj / 7, w2j = rj - w1j * 7;
                int rel = (li - lj + AGENT - 1) * 169 + (w1i - w1j + WIN - 1) * 13 + (w2i - w2j + WIN - 1);
                val = rdf(bt, (size_t)rel * HEADS + h, isf32) * LOG2E;
            }
            v[r] = val;
        }
        ((f32x4*)biasB)[idx] = v;
    } else {
        int c = (bid - 722) * 256 + threadIdx.x;   // chunk of 8 elems
        const void* src; unsigned short* dst; size_t off;
        if (c < 24576) { src = wq; dst = Wq; off = (size_t)c * 8; }
        else           { src = wo; dst = Wo; off = (size_t)(c - 24576) * 8; }
        if (isf32) {
            const float4* s4 = (const float4*)((const float*)src + off);
            float4 v0 = s4[0], v1 = s4[1];
            s16x8 u;
            u[0] = (short)f2bu(v0.x); u[1] = (short)f2bu(v0.y); u[2] = (short)f2bu(v0.z); u[3] = (short)f2bu(v0.w);
            u[4] = (short)f2bu(v1.x); u[5] = (short)f2bu(v1.y); u[6] = (short)f2bu(v1.z); u[7] = (short)f2bu(v1.w);
            *(s16x8*)(dst + off) = u;
        } else {
            *(uint4*)(dst + off) = *(const uint4*)((const unsigned short*)src + off);
        }
    }
}

// stage a 64x256 bf16 tile into LINEAR LDS via global_load_lds, T2 XOR swizzle
// applied on the GLOBAL source address: LDS[row][c'] = G[row][c' ^ (row&7)*8]
__device__ __forceinline__ void stage64_g(const unsigned short* __restrict__ g,
                                          unsigned short* lds, size_t rowBase) {
    const int lane = threadIdx.x & 63, wv = threadIdx.x >> 6;
    const int sub = lane >> 5;
    const int colB = (lane & 31) << 4;
    #pragma unroll
    for (int k = 0; k < 8; k++) {
        const int rr = (wv * 8 + k) * 2 + sub;
        const int cg = colB ^ ((rr & 7) << 4);
        gll16((const char*)g + (rowBase + (size_t)rr) * 512 + cg,
              lds + (size_t)(wv * 8 + k) * 512);
    }
}

// f32 source variant for x: reg-stage + convert + swizzled ds_write, NT loads
__device__ __forceinline__ void stage64_f(const float* __restrict__ g,
                                          unsigned short* lds, size_t rowBase) {
    const int tid = threadIdx.x;
    #pragma unroll
    for (int k = 0; k < 8; k++) {
        int ch = k * 256 + tid;
        int rr = ch >> 5;
        int cB = (ch & 31) << 4;
        int cg = cB ^ ((rr & 7) << 4);
        const f32x4* s4 = (const f32x4*)(g + (rowBase + (size_t)rr) * 256 + (cg >> 1));
        f32x4 v0 = __builtin_nontemporal_load(s4);
        f32x4 v1 = __builtin_nontemporal_load(s4 + 1);
        s16x8 u;
        u[0] = (short)f2bu(v0[0]); u[1] = (short)f2bu(v0[1]); u[2] = (short)f2bu(v0[2]); u[3] = (short)f2bu(v0[3]);
        u[4] = (short)f2bu(v1[0]); u[5] = (short)f2bu(v1[1]); u[6] = (short)f2bu(v1[2]); u[7] = (short)f2bu(v1[3]);
        *(s16x8*)(lds + (size_t)rr * 256 + (cB >> 1)) = u;
    }
}

// ---------- QKV MFMA GEMM (R4 structure): As staged once, Bs streamed 12 x 64-col ----------
__global__ __launch_bounds__(256) void qkv_mfma(
    const void* __restrict__ xin, const unsigned short* __restrict__ Wq,
    bf16* __restrict__ Q, bf16* __restrict__ K, bf16* __restrict__ V) {
    __shared__ unsigned short As[64 * 256];
    __shared__ unsigned short Bs[64 * 256];
    __shared__ int sflag;
    const int isf32 = detect_flag((const unsigned short*)xin, &sflag, 256);
    const size_t mBase = (size_t)blockIdx.x * 64;
    if (isf32) stage64_f((const float*)xin, As, mBase);
    else       stage64_g((const unsigned short*)xin, As, mBase);
    const int tid = threadIdx.x;
    const int wave = tid >> 6, lane = tid & 63;
    const int li = lane & 15, g = lane >> 4;
    const int wm = wave & 1, wn = wave >> 1;
    unsigned int rowOff[2][4];
    #pragma unroll
    for (int mi = 0; mi < 2; mi++)
        #pragma unroll
        for (int r = 0; r < 4; r++) {
            unsigned int m = (unsigned int)mBase + wm * 32 + mi * 16 + g * 4 + r;
            unsigned int w2 = m % 7u, t1 = m / 7u;
            unsigned int w1 = t1 % 7u, t2 = t1 / 7u;
            unsigned int yy = t2 & 7u, t3 = t2 >> 3;
            unsigned int xx = t3 & 7u, t4 = t3 >> 3;
            unsigned int l = t4 % 6u, b = t4 / 6u;
            unsigned int bw = (b << 6) | (xx << 3) | yy;
            unsigned int n = l * 49u + w1 * 7u + w2;
            rowOff[mi][r] = bw * 75264u + n * 32u;   // + h*9408 + d at store
        }
    const int koX = (li & 7) * 8;
    for (int pc = 0; pc < 12; pc++) {
        __syncthreads();                       // prev chunk's Bs reads done (WAR)
        stage64_g(Wq, Bs, (size_t)pc * 64);
        __syncthreads();                       // vmcnt drain -> Bs (and As at pc=0) ready
        f32x4 acc[2][2];
        #pragma unroll
        for (int mi = 0; mi < 2; mi++)
            #pragma unroll
            for (int ni = 0; ni < 2; ni++) acc[mi][ni] = (f32x4){0.f, 0.f, 0.f, 0.f};
        #pragma unroll
        for (int kc = 0; kc < 8; kc++) {
            const int ko = (kc * 32 + g * 8) ^ koX;
            s16x8 a0 = *(const s16x8*)&As[(wm * 32 + li) * 256 + ko];
            s16x8 a1 = *(const s16x8*)&As[(wm * 32 + 16 + li) * 256 + ko];
            s16x8 b0 = *(const s16x8*)&Bs[(wn * 32 + li) * 256 + ko];
            s16x8 b1 = *(const s16x8*)&Bs[(wn * 32 + 16 + li) * 256 + ko];
            acc[0][0] = __builtin_amdgcn_mfma_f32_16x16x32_bf16(a0, b0, acc[0][0], 0, 0, 0);
            acc[0][1] = __builtin_amdgcn_mfma_f32_16x16x32_bf16(a0, b1, acc[0][1], 0, 0, 0);
            acc[1][0] = __builtin_amdgcn_mfma_f32_16x16x32_bf16(a1, b0, acc[1][0], 0, 0, 0);
            acc[1][1] = __builtin_amdgcn_mfma_f32_16x16x32_bf16(a1, b1, acc[1][1], 0, 0, 0);
        }
        const int p = pc >> 2;                  // 0:Q 1:K 2:V
        bf16* dst = (p == 0) ? Q : (p == 1) ? K : V;
        const float sc = (p == 0) ? (SCALE * LOG2E) : 1.0f;
        const unsigned int hoff = ((pc & 3) * 2 + wn) * 9408u;
        #pragma unroll
        for (int ni = 0; ni < 2; ni++) {
            const unsigned int d = ni * 16 + li;
            #pragma unroll
            for (int mi = 0; mi < 2; mi++)
                #pragma unroll
                for (int r = 0; r < 4; r++)
                    dst[(size_t)(rowOff[mi][r] + hoff + d)] =
                        __float2bfloat16(acc[mi][ni][r] * sc);
        }
    }
}

// ---------- MFMA attention: R4 shuffle-PV + f32 bias + mask-at-exp ----------
__global__ __launch_bounds__(512, 2) void attn_mfma(
    const bf16* __restrict__ Q, const bf16* __restrict__ K, const bf16* __restrict__ V,
    const float* __restrict__ biasB, const int* __restrict__ mask,
    bf16* __restrict__ AT) {
    __shared__ unsigned short Qs[304 * QSTR];
    __shared__ unsigned short Ks[304 * QSTR];
    __shared__ unsigned short Vt[32 * PSTR];
    __shared__ int ms[320];
    const int tid = threadIdx.x;
    const int bw = blockIdx.x >> 3, h = blockIdx.x & 7;
    const size_t base = ((size_t)bw * HEADS + h) * NTOK * DH;
    const unsigned int* Qg = (const unsigned int*)(Q + base);
    const unsigned int* Kg = (const unsigned int*)(K + base);
    const unsigned int* Vg = (const unsigned int*)(V + base);
    char* VtB = (char*)Vt;
    for (int gg = tid; gg < NTOK * DH / 2; gg += 512) {
        int r = gg >> 4, d2 = (gg & 15) * 2;
        unsigned int uq = __builtin_nontemporal_load(&Qg[gg]);
        unsigned int uk = __builtin_nontemporal_load(&Kg[gg]);
        unsigned int uv = __builtin_nontemporal_load(&Vg[gg]);
        *(unsigned int*)&Qs[r * QSTR + d2] = uq;
        *(unsigned int*)&Ks[r * QSTR + d2] = uk;
        *(unsigned short*)(VtB + vtswz(d2,     r * 2)) = (unsigned short)(uv & 0xffffu);
        *(unsigned short*)(VtB + vtswz(d2 + 1, r * 2)) = (unsigned short)(uv >> 16);
    }
    for (int e = NTOK * QSTR + tid; e < 304 * QSTR; e += 512) { Qs[e] = 0; Ks[e] = 0; }
    for (int idx = tid; idx < 32 * (PSTR - NTOK); idx += 512) {
        int d = idx / (PSTR - NTOK), c = NTOK + idx % (PSTR - NTOK);
        *(unsigned short*)(VtB + vtswz(d, c * 2)) = 0;
    }
    for (int j = tid; j < 320; j += 512) {
        int mv = 0;
        if (j < NTOK) { int a = j / 49, jr = j - a * 49; mv = mask[((size_t)bw * 49 + jr) * AGENT + a]; }
        ms[j] = mv;
    }
    __syncthreads();
    const int wave = tid >> 6, lane = tid & 63;
    const int li = lane & 15, g = lane >> 4;
    unsigned int mb0 = 0, mb1 = 0, mb2 = 0;
    for (int jt = 0; jt < TP; jt++)
        for (int r = 0; r < 4; r++) {
            int j = jt * 16 + g * 4 + r;
            if (j < NTOK && ms[j]) {
                int bit = jt * 4 + r;
                if (bit < 32) mb0 |= (1u << bit);
                else if (bit < 64) mb1 |= (1u << (bit - 32));
                else mb2 |= (1u << (bit - 64));
            }
        }
    const f32x4* bb = (const f32x4*)biasB + (size_t)h * TP * TP * 64;
    const int sAg = li + ((lane & 16) << 1);   // li + 32*(g&1)
    const int sBg = sAg + 16;
    const bool hiSel = (lane >= 32);           // g>>1
    for (int it = wave; it < TP; it += 8) {
        const s16x8 bq = *(const s16x8*)&Qs[(it * 16 + li) * QSTR + g * 8];
        f32x4 s[TP];
        __builtin_amdgcn_s_setprio(1);
        #pragma unroll
        for (int jt = 0; jt < TP; jt++) {
            f32x4 c = bb[(it * TP + jt) * 64 + lane];
            s16x8 ak = *(const s16x8*)&Ks[(jt * 16 + li) * QSTR + g * 8];
            s[jt] = __builtin_amdgcn_mfma_f32_16x16x32_bf16(ak, bq, c, 0, 0, 0);
        }
        __builtin_amdgcn_s_setprio(0);
        // raw max (safe: mx >= true masked max only rescales num+den identically;
        // masked/pad entries are zeroed at exp). Two independent chains.
        float m0 = -3e38f, m1 = -3e38f;
        #pragma unroll
        for (int jt = 0; jt < TP; jt++) {
            m0 = fmaxf(m0, fmaxf(s[jt][0], s[jt][1]));
            m1 = fmaxf(m1, fmaxf(s[jt][2], s[jt][3]));
        }
        float mx = fmaxf(m0, m1);
        mx = fmaxf(mx, __shfl_xor(mx, 16));
        mx = fmaxf(mx, __shfl_xor(mx, 32));
        // exp2 + mask-zero + in-register bf16 pack (unnormalized P)
        float sum = 0.f;
        unsigned int p0[TP], p1[TP];
        #pragma unroll
        for (int jt = 0; jt < TP; jt++) {
            const int bit = jt * 4;
            const unsigned int w = (bit < 32) ? mb0 : (bit < 64) ? mb1 : mb2;
            const int bs = bit & 31;
            float e0 = ((w >> bs) & 1u)       ? EXP2(s[jt][0] - mx) : 0.f;
            float e1 = ((w >> (bs + 1)) & 1u) ? EXP2(s[jt][1] - mx) : 0.f;
            float e2 = ((w >> (bs + 2)) & 1u) ? EXP2(s[jt][2] - mx) : 0.f;
            float e3 = ((w >> (bs + 3)) & 1u) ? EXP2(s[jt][3] - mx) : 0.f;
            sum += (e0 + e1) + (e2 + e3);
            unsigned int lo, hi;
            asm("v_cvt_pk_bf16_f32 %0, %1, %2" : "=v"(lo) : "v"(e0), "v"(e1));
            asm("v_cvt_pk_bf16_f32 %0, %1, %2" : "=v"(hi) : "v"(e2), "v"(e3));
            p0[jt] = lo; p1[jt] = hi;
        }
        sum += __shfl_xor(sum, 16);
        sum += __shfl_xor(sum, 32);
        const float inv = 1.0f / sum;
        // PV: A-fragment via ds_bpermute shuffles (LDS pipe; overlaps VALU)
        f32x4 o0 = {0.f, 0.f, 0.f, 0.f}, o1 = {0.f, 0.f, 0.f, 0.f};
        #pragma unroll
        for (int kc = 0; kc < 10; kc++) {
            unsigned int a0q = __shfl(p0[2 * kc], sAg);
            unsigned int b0q = __shfl(p1[2 * kc], sAg);
            unsigned int c0q = __shfl(p0[2 * kc], sBg);
            unsigned int d0q = __shfl(p1[2 * kc], sBg);
            unsigned int a1q = 0, b1q = 0, c1q = 0, d1q = 0;
            if (2 * kc + 1 < TP) {
                a1q = __shfl(p0[2 * kc + 1], sAg);
                b1q = __shfl(p1[2 * kc + 1], sAg);
                c1q = __shfl(p0[2 * kc + 1], sBg);
                d1q = __shfl(p1[2 * kc + 1], sBg);
            }
            u32x4 w;
            w[0] = hiSel ? a1q : a0q;
            w[1] = hiSel ? b1q : b0q;
            w[2] = hiSel ? c1q : c0q;
            w[3] = hiSel ? d1q : d0q;
            s16x8 ap = __builtin_bit_cast(s16x8, w);
            s16x8 b0 = *(const s16x8*)(VtB + vtswz(li,      (kc * 32 + g * 8) * 2));
            s16x8 b1 = *(const s16x8*)(VtB + vtswz(li + 16, (kc * 32 + g * 8) * 2));
            __builtin_amdgcn_s_setprio(1);
            o0 = __builtin_amdgcn_mfma_f32_16x16x32_bf16(ap, b0, o0, 0, 0, 0);
            o1 = __builtin_amdgcn_mfma_f32_16x16x32_bf16(ap, b1, o1, 0, 0, 0);
            __builtin_amdgcn_s_setprio(0);
        }
        #pragma unroll
        for (int r = 0; r < 4; r++) {
            float iv = __shfl(inv, g * 4 + r);
            int i = it * 16 + g * 4 + r;
            if (i < NTOK) {
                size_t ob = ((size_t)bw * NTOK + i) * DIM + h * DH;
                AT[ob + li]      = __float2bfloat16(o0[r] * iv);
                AT[ob + 16 + li] = __float2bfloat16(o1[r] * iv);
            }
        }
    }
}

// ---------- proj MFMA GEMM (R4 structure): gll-staged, f32 NT out ----------
__global__ __launch_bounds__(256) void proj_mfma(
    const bf16* __restrict__ AT, const unsigned short* __restrict__ Wo,
    float* __restrict__ out) {
    __shared__ unsigned short As[64 * 256];
    __shared__ unsigned short Bs[64 * 256];
    const size_t mBase = (size_t)blockIdx.x * 64;
    stage64_g((const unsigned short*)AT, As, mBase);
    const int tid = threadIdx.x;
    const int wave = tid >> 6, lane = tid & 63;
    const int li = lane & 15, g = lane >> 4;
    const int wm = wave & 1, wn = wave >> 1;
    unsigned int offO[2][4];
    #pragma unroll
    for (int mi = 0; mi < 2; mi++)
        #pragma unroll
        for (int r = 0; r < 4; r++) {
            unsigned int m = (unsigned int)mBase + wm * 32 + mi * 16 + g * 4 + r;
            unsigned int bw = m / 294u, n = m - bw * 294u;
            unsigned int b = bw >> 6, xx = (bw >> 3) & 7u, yy = bw & 7u;
            unsigned int l = n / 49u, rr = n - l * 49u, w1 = rr / 7u, w2 = rr - w1 * 7u;
            offO[mi][r] = ((((((b * 6u + l) * 8u + xx) * 8u + yy) * 7u + w1) * 7u) + w2) * 256u;
        }
    const int koX = (li & 7) * 8;
    for (int ec = 0; ec < 4; ec++) {
        __syncthreads();
        stage64_g(Wo, Bs, (size_t)ec * 64);
        __syncthreads();
        f32x4 acc[2][2];
        #pragma unroll
        for (int mi = 0; mi < 2; mi++)
            #pragma unroll
            for (int ni = 0; ni < 2; ni++) acc[mi][ni] = (f32x4){0.f, 0.f, 0.f, 0.f};
        #pragma unroll
        for (int kc = 0; kc < 8; kc++) {
            const int ko = (kc * 32 + g * 8) ^ koX;
            s16x8 a0 = *(const s16x8*)&As[(wm * 32 + li) * 256 + ko];
            s16x8 a1 = *(const s16x8*)&As[(wm * 32 + 16 + li) * 256 + ko];
            s16x8 b0 = *(const s16x8*)&Bs[(wn * 32 + li) * 256 + ko];
            s16x8 b1 = *(const s16x8*)&Bs[(wn * 32 + 16 + li) * 256 + ko];
            acc[0][0] = __builtin_amdgcn_mfma_f32_16x16x32_bf16(a0, b0, acc[0][0], 0, 0, 0);
            acc[0][1] = __builtin_amdgcn_mfma_f32_16x16x32_bf16(a0, b1, acc[0][1], 0, 0, 0);
            acc[1][0] = __builtin_amdgcn_mfma_f32_16x16x32_bf16(a1, b0, acc[1][0], 0, 0, 0);
            acc[1][1] = __builtin_amdgcn_mfma_f32_16x16x32_bf16(a1, b1, acc[1][1], 0, 0, 0);
        }
        #pragma unroll
        for (int ni = 0; ni < 2; ni++) {
            const unsigned int e = ec * 64 + wn * 32 + ni * 16 + li;
            #pragma unroll
            for (int mi = 0; mi < 2; mi++)
                #pragma unroll
                for (int r = 0; r < 4; r++)
                    __builtin_nontemporal_store(acc[mi][ni][r],
                        &out[(size_t)(offO[mi][r] + e)]);
        }
    }
}

extern "C" void kernel_launch(void* const* d_in, const int* in_sizes, int n_in,
                              void* d_out, int out_size, void* d_ws, size_t ws_size,
                              hipStream_t stream) {
    const long long SZ_X = 9633792, SZ_M = 37632, SZ_WQ = 196608, SZ_WO = 65536, SZ_BT = 14872;
    const void* x = d_in[0]; const void* maskp = d_in[1]; const void* wqkv = d_in[2];
    const void* wout = d_in[3]; const void* btab = d_in[4];
    for (int i = 0; i < n_in; i++) {
        long long s = in_sizes[i];
        if (s == SZ_X) x = d_in[i];
        else if (s == SZ_M) maskp = d_in[i];
        else if (s == SZ_WQ) wqkv = d_in[i];
        else if (s == SZ_WO) wout = d_in[i];
        else if (s == SZ_BT) btab = d_in[i];
    }
    const int* mask = (const int*)maskp;
    float* out = (float*)d_out;
    const size_t SZ = (size_t)BWIN * NTOK * DIM;
    bf16* Q  = (bf16*)d_ws;
    bf16* K  = Q + SZ;
    bf16* V  = K + SZ;
    bf16* AT = V + SZ;
    float* biasB = (float*)(AT + SZ);
    const size_t NBBf = (size_t)HEADS * TP * TP * 64 * 4;   // f32 elems
    unsigned short* Wq = (unsigned short*)(biasB + NBBf);
    unsigned short* Wo = Wq + 196608;
    prep_kernel<<<dim3(850), dim3(256), 0, stream>>>(
        (const unsigned short*)x, wqkv, wout, btab, Wq, Wo, biasB);
    qkv_mfma<<<dim3(588), dim3(256), 0, stream>>>(x, Wq, Q, K, V);
    attn_mfma<<<dim3(BWIN * HEADS), dim3(512), 0, stream>>>(Q, K, V, biasB, mask, AT);
    proj_mfma<<<dim3(588), dim3(256), 0, stream>>>(AT, Wo, out);
}

// Round 9
// 209.089 us; speedup vs baseline: 1.0611x; 1.0611x over previous
//
#include <hip/hip_runtime.h>
#include <hip/hip_bf16.h>

#define DIM 256
#define HEADS 8
#define DH 32
#define AGENT 6
#define WIN 7
#define NTOK 294              // AGENT*WIN*WIN
#define BWIN 128              // B*X*Y = 2*8*8
#define SCALE 0.17677669529663687f  // 32^-0.5
#define LOG2E 1.4426950408889634f
#define TP 19                 // 16-row tiles covering 294 (padded to 304)
#define QSTR 40               // attn Qs/Ks LDS row stride
#define PSTR 320              // attn Vt LDS row stride: 640B = 5*128B (row 128B-aligned)

typedef __hip_bfloat16 bf16;
typedef __attribute__((ext_vector_type(8))) short s16x8;
typedef __attribute__((ext_vector_type(4))) float f32x4;
typedef __attribute__((ext_vector_type(4))) unsigned int u32x4;

#if __has_builtin(__builtin_amdgcn_exp2f)
#define EXP2(x) __builtin_amdgcn_exp2f(x)
#else
#define EXP2(x) exp2f(x)
#endif

__device__ __forceinline__ float bfv(unsigned short u){ return __uint_as_float(((unsigned int)u) << 16); }
__device__ __forceinline__ unsigned short f2bu(float f){
    bf16 b = __float2bfloat16(f); return *reinterpret_cast<unsigned short*>(&b);
}
__device__ __forceinline__ float rdf(const void* p, size_t idx, int isf32) {
    return isf32 ? ((const float*)p)[idx] : bfv(((const unsigned short*)p)[idx]);
}

// Vt byte-address swizzle: row d (128B-aligned, 640B), XOR key permutes 16B slots
// within each 128B block; bijective per row.
__device__ __forceinline__ int vtswz(int d, int cByte) {
    return (d * (PSTR * 2) + cByte) ^ (((d >> 1) & 7) << 4);
}

// async global->LDS, 16B per lane. LDS dest = uniform base + lane*16 (linear).
__device__ __forceinline__ void gll16(const void* gp, void* lp) {
    __builtin_amdgcn_global_load_lds(
        (const __attribute__((address_space(1))) unsigned int*)gp,
        (__attribute__((address_space(3))) unsigned int*)lp, 16, 0, 0);
}

// inline dtype detect: flag=1 -> f32 inputs, flag=0 -> bf16. Pure function of x.
__device__ __forceinline__ int detect_flag(const unsigned short* __restrict__ xraw,
                                           int* sflag, int nthreads) {
    if (threadIdx.x == 0) *sflag = 0;
    __syncthreads();
    int bad = 0;
    for (int i = threadIdx.x; i < 8192; i += nthreads) {
        float v = bfv(xraw[i]);
        if (!(fabsf(v) <= 1e10f)) bad = 1;
    }
    if (bad) atomicOr(sflag, 1);
    __syncthreads();
    return *sflag;
}

// ---------- prep: detect + bias(bf16,LOG2E) + W materialize (R4 structure) ----------
// blocks [0,722): biasB ; [722,850): Wq/Wo
__global__ __launch_bounds__(256) void prep_kernel(
    const unsigned short* __restrict__ xraw,
    const void* __restrict__ wq, const void* __restrict__ wo, const void* __restrict__ bt,
    unsigned short* __restrict__ Wq, unsigned short* __restrict__ Wo,
    unsigned short* __restrict__ biasB) {
    __shared__ int sflag;
    const int isf32 = detect_flag(xraw, &sflag, 256);
    const int bid = blockIdx.x;
    if (bid < 722) {
        int idx = bid * 256 + threadIdx.x;
        int lane = idx & 63; int t = idx >> 6;
        int jt = t % TP; t /= TP; int it = t % TP; int h = t / TP;
        int i = it * 16 + (lane & 15);
        int g = lane >> 4;
        ushort4 v;
        unsigned short* vp = (unsigned short*)&v;
        #pragma unroll
        for (int r = 0; r < 4; r++) {
            int j = jt * 16 + g * 4 + r;
            float val = 0.f;
            if (i < NTOK && j < NTOK) {
                int li = i / 49, ri = i - li * 49, w1i = ri / 7, w2i = ri - w1i * 7;
                int lj = j / 49, rj = j - lj * 49, w1j = rj / 7, w2j = rj - w1j * 7;
                int rel = (li - lj + AGENT - 1) * 169 + (w1i - w1j + WIN - 1) * 13 + (w2i - w2j + WIN - 1);
                val = rdf(bt, (size_t)rel * HEADS + h, isf32) * LOG2E;
            }
            vp[r] = f2bu(val);
        }
        ((ushort4*)biasB)[idx] = v;
    } else {
        int c = (bid - 722) * 256 + threadIdx.x;   // chunk of 8 elems
        const void* src; unsigned short* dst; size_t off;
        if (c < 24576) { src = wq; dst = Wq; off = (size_t)c * 8; }
        else           { src = wo; dst = Wo; off = (size_t)(c - 24576) * 8; }
        if (isf32) {
            const float4* s4 = (const float4*)((const float*)src + off);
            float4 v0 = s4[0], v1 = s4[1];
            s16x8 u;
            u[0] = (short)f2bu(v0.x); u[1] = (short)f2bu(v0.y); u[2] = (short)f2bu(v0.z); u[3] = (short)f2bu(v0.w);
            u[4] = (short)f2bu(v1.x); u[5] = (short)f2bu(v1.y); u[6] = (short)f2bu(v1.z); u[7] = (short)f2bu(v1.w);
            *(s16x8*)(dst + off) = u;
        } else {
            *(uint4*)(dst + off) = *(const uint4*)((const unsigned short*)src + off);
        }
    }
}

// stage a 64x256 bf16 tile into LINEAR LDS via global_load_lds, T2 XOR swizzle
// applied on the GLOBAL source address: LDS[row][c'] = G[row][c' ^ (row&7)*8]
__device__ __forceinline__ void stage64_g(const unsigned short* __restrict__ g,
                                          unsigned short* lds, size_t rowBase) {
    const int lane = threadIdx.x & 63, wv = threadIdx.x >> 6;
    const int sub = lane >> 5;
    const int colB = (lane & 31) << 4;
    #pragma unroll
    for (int k = 0; k < 8; k++) {
        const int rr = (wv * 8 + k) * 2 + sub;
        const int cg = colB ^ ((rr & 7) << 4);
        gll16((const char*)g + (rowBase + (size_t)rr) * 512 + cg,
              lds + (size_t)(wv * 8 + k) * 512);
    }
}

// f32 source variant for x: reg-stage + convert + swizzled ds_write, NT loads
__device__ __forceinline__ void stage64_f(const float* __restrict__ g,
                                          unsigned short* lds, size_t rowBase) {
    const int tid = threadIdx.x;
    #pragma unroll
    for (int k = 0; k < 8; k++) {
        int ch = k * 256 + tid;
        int rr = ch >> 5;
        int cB = (ch & 31) << 4;
        int cg = cB ^ ((rr & 7) << 4);
        const f32x4* s4 = (const f32x4*)(g + (rowBase + (size_t)rr) * 256 + (cg >> 1));
        f32x4 v0 = __builtin_nontemporal_load(s4);
        f32x4 v1 = __builtin_nontemporal_load(s4 + 1);
        s16x8 u;
        u[0] = (short)f2bu(v0[0]); u[1] = (short)f2bu(v0[1]); u[2] = (short)f2bu(v0[2]); u[3] = (short)f2bu(v0[3]);
        u[4] = (short)f2bu(v1[0]); u[5] = (short)f2bu(v1[1]); u[6] = (short)f2bu(v1[2]); u[7] = (short)f2bu(v1[3]);
        *(s16x8*)(lds + (size_t)rr * 256 + (cB >> 1)) = u;
    }
}

// ---------- QKV MFMA GEMM: reg-resident A, aliased double-buffered Bs, 1 barrier/chunk ----------
// As staged directly from x (once per block, as in R4); P1 then recycled for odd B chunks.
__global__ __launch_bounds__(256) void qkv_mfma(
    const void* __restrict__ xin, const unsigned short* __restrict__ Wq,
    bf16* __restrict__ Q, bf16* __restrict__ K, bf16* __restrict__ V) {
    __shared__ unsigned short P0[64 * 256];    // Bs even chunks
    __shared__ unsigned short P1[64 * 256];    // As (transient), then Bs odd chunks
    __shared__ int sflag;
    const int isf32 = detect_flag((const unsigned short*)xin, &sflag, 256);
    const size_t mBase = (size_t)blockIdx.x * 64;
    if (isf32) stage64_f((const float*)xin, P1, mBase);        // As
    else       stage64_g((const unsigned short*)xin, P1, mBase);
    stage64_g(Wq, P0, 0);                      // Bs chunk 0
    const int tid = threadIdx.x;
    const int wave = tid >> 6, lane = tid & 63;
    const int li = lane & 15, g = lane >> 4;
    const int wm = wave & 1, wn = wave >> 1;
    unsigned int rowOff[2][4];
    #pragma unroll
    for (int mi = 0; mi < 2; mi++)
        #pragma unroll
        for (int r = 0; r < 4; r++) {
            unsigned int m = (unsigned int)mBase + wm * 32 + mi * 16 + g * 4 + r;
            unsigned int w2 = m % 7u, t1 = m / 7u;
            unsigned int w1 = t1 % 7u, t2 = t1 / 7u;
            unsigned int yy = t2 & 7u, t3 = t2 >> 3;
            unsigned int xx = t3 & 7u, t4 = t3 >> 3;
            unsigned int l = t4 % 6u, b = t4 / 6u;
            unsigned int bw = (b << 6) | (xx << 3) | yy;
            unsigned int n = l * 49u + w1 * 7u + w2;
            rowOff[mi][r] = bw * 75264u + n * 32u;   // + h*9408 + d at store
        }
    const int koX = (li & 7) * 8;
    __syncthreads();                           // As + Bs0 resident (vmcnt/lgkm drained)
    // preload A fragments to registers (frees P1 for Bs odd chunks)
    s16x8 a0r[8], a1r[8];
    #pragma unroll
    for (int kc = 0; kc < 8; kc++) {
        const int ko = (kc * 32 + g * 8) ^ koX;
        a0r[kc] = *(const s16x8*)&P1[(wm * 32 + li) * 256 + ko];
        a1r[kc] = *(const s16x8*)&P1[(wm * 32 + 16 + li) * 256 + ko];
    }
    __syncthreads();                           // all A reads done before P1 overwrite
    for (int c = 0; c < 12; c++) {
        const unsigned short* Bc = (c & 1) ? P1 : P0;
        unsigned short* Bn = (c & 1) ? P0 : P1;
        if (c + 1 < 12) stage64_g(Wq, Bn, (size_t)(c + 1) * 64);  // fly during compute
        f32x4 acc[2][2];
        #pragma unroll
        for (int mi = 0; mi < 2; mi++)
            #pragma unroll
            for (int ni = 0; ni < 2; ni++) acc[mi][ni] = (f32x4){0.f, 0.f, 0.f, 0.f};
        #pragma unroll
        for (int kc = 0; kc < 8; kc++) {
            const int ko = (kc * 32 + g * 8) ^ koX;
            s16x8 b0 = *(const s16x8*)&Bc[(wn * 32 + li) * 256 + ko];
            s16x8 b1 = *(const s16x8*)&Bc[(wn * 32 + 16 + li) * 256 + ko];
            acc[0][0] = __builtin_amdgcn_mfma_f32_16x16x32_bf16(a0r[kc], b0, acc[0][0], 0, 0, 0);
            acc[0][1] = __builtin_amdgcn_mfma_f32_16x16x32_bf16(a0r[kc], b1, acc[0][1], 0, 0, 0);
            acc[1][0] = __builtin_amdgcn_mfma_f32_16x16x32_bf16(a1r[kc], b0, acc[1][0], 0, 0, 0);
            acc[1][1] = __builtin_amdgcn_mfma_f32_16x16x32_bf16(a1r[kc], b1, acc[1][1], 0, 0, 0);
        }
        const int p = c >> 2;                  // 0:Q 1:K 2:V
        bf16* dst = (p == 0) ? Q : (p == 1) ? K : V;
        const float sc = (p == 0) ? (SCALE * LOG2E) : 1.0f;
        const unsigned int hoff = ((c & 3) * 2 + wn) * 9408u;
        #pragma unroll
        for (int ni = 0; ni < 2; ni++) {
            const unsigned int d = ni * 16 + li;
            #pragma unroll
            for (int mi = 0; mi < 2; mi++)
                #pragma unroll
                for (int r = 0; r < 4; r++)
                    dst[(size_t)(rowOff[mi][r] + hoff + d)] =
                        __float2bfloat16(acc[mi][ni][r] * sc);
        }
        __syncthreads();                       // drain stage(c+1); WAR for next overwrite
    }
}

// ---------- MFMA attention: EXACT R4 (known 71.5 us) ----------
__global__ __launch_bounds__(512, 2) void attn_mfma(
    const bf16* __restrict__ Q, const bf16* __restrict__ K, const bf16* __restrict__ V,
    const unsigned short* __restrict__ biasB, const int* __restrict__ mask,
    bf16* __restrict__ AT) {
    __shared__ unsigned short Qs[304 * QSTR];
    __shared__ unsigned short Ks[304 * QSTR];
    __shared__ unsigned short Vt[32 * PSTR];
    __shared__ int ms[320];
    const int tid = threadIdx.x;
    const int bw = blockIdx.x >> 3, h = blockIdx.x & 7;
    const size_t base = ((size_t)bw * HEADS + h) * NTOK * DH;
    const unsigned int* Qg = (const unsigned int*)(Q + base);
    const unsigned int* Kg = (const unsigned int*)(K + base);
    const unsigned int* Vg = (const unsigned int*)(V + base);
    char* VtB = (char*)Vt;
    for (int gg = tid; gg < NTOK * DH / 2; gg += 512) {
        int r = gg >> 4, d2 = (gg & 15) * 2;
        unsigned int uq = __builtin_nontemporal_load(&Qg[gg]);
        unsigned int uk = __builtin_nontemporal_load(&Kg[gg]);
        unsigned int uv = __builtin_nontemporal_load(&Vg[gg]);
        *(unsigned int*)&Qs[r * QSTR + d2] = uq;
        *(unsigned int*)&Ks[r * QSTR + d2] = uk;
        *(unsigned short*)(VtB + vtswz(d2,     r * 2)) = (unsigned short)(uv & 0xffffu);
        *(unsigned short*)(VtB + vtswz(d2 + 1, r * 2)) = (unsigned short)(uv >> 16);
    }
    for (int e = NTOK * QSTR + tid; e < 304 * QSTR; e += 512) { Qs[e] = 0; Ks[e] = 0; }
    for (int idx = tid; idx < 32 * (PSTR - NTOK); idx += 512) {
        int d = idx / (PSTR - NTOK), c = NTOK + idx % (PSTR - NTOK);
        *(unsigned short*)(VtB + vtswz(d, c * 2)) = 0;
    }
    for (int j = tid; j < 320; j += 512) {
        int mv = 0;
        if (j < NTOK) { int a = j / 49, jr = j - a * 49; mv = mask[((size_t)bw * 49 + jr) * AGENT + a]; }
        ms[j] = mv;
    }
    __syncthreads();
    const int wave = tid >> 6, lane = tid & 63;
    const int li = lane & 15, g = lane >> 4;
    unsigned int mb0 = 0, mb1 = 0, mb2 = 0;
    for (int jt = 0; jt < TP; jt++)
        for (int r = 0; r < 4; r++) {
            int j = jt * 16 + g * 4 + r;
            if (j < NTOK && ms[j]) {
                int bit = jt * 4 + r;
                if (bit < 32) mb0 |= (1u << bit);
                else if (bit < 64) mb1 |= (1u << (bit - 32));
                else mb2 |= (1u << (bit - 64));
            }
        }
    const ushort4* bb = (const ushort4*)biasB + (size_t)h * TP * TP * 64;
    const int sAg = li + ((lane & 16) << 1);   // li + 32*(g&1)
    const int sBg = sAg + 16;
    const bool hiSel = (lane >= 32);           // g>>1
    for (int it = wave; it < TP; it += 8) {
        const s16x8 bq = *(const s16x8*)&Qs[(it * 16 + li) * QSTR + g * 8];
        f32x4 s[TP];
        __builtin_amdgcn_s_setprio(1);
        #pragma unroll
        for (int jt = 0; jt < TP; jt++) {
            ushort4 bv = bb[(it * TP + jt) * 64 + lane];
            f32x4 c = {bfv(bv.x), bfv(bv.y), bfv(bv.z), bfv(bv.w)};
            s16x8 ak = *(const s16x8*)&Ks[(jt * 16 + li) * QSTR + g * 8];
            s[jt] = __builtin_amdgcn_mfma_f32_16x16x32_bf16(ak, bq, c, 0, 0, 0);
        }
        __builtin_amdgcn_s_setprio(0);
        float mx = -INFINITY;
        #pragma unroll
        for (int jt = 0; jt < TP; jt++)
            #pragma unroll
            for (int r = 0; r < 4; r++) {
                int bit = jt * 4 + r;
                unsigned int w = (bit < 32) ? mb0 : (bit < 64) ? mb1 : mb2;
                float sv = ((w >> (bit & 31)) & 1u) ? s[jt][r] : -1e9f;
                if (jt == TP - 1 && g * 4 + r >= 6) sv = -INFINITY;
                s[jt][r] = sv;
                mx = fmaxf(mx, sv);
            }
        mx = fmaxf(mx, __shfl_xor(mx, 16));
        mx = fmaxf(mx, __shfl_xor(mx, 32));
        float sum = 0.f;
        unsigned int p0[TP], p1[TP];
        #pragma unroll
        for (int jt = 0; jt < TP; jt++) {
            float e0 = EXP2(s[jt][0] - mx);
            float e1 = EXP2(s[jt][1] - mx);
            float e2 = EXP2(s[jt][2] - mx);
            float e3 = EXP2(s[jt][3] - mx);
            sum += (e0 + e1) + (e2 + e3);
            unsigned int lo, hi;
            asm("v_cvt_pk_bf16_f32 %0, %1, %2" : "=v"(lo) : "v"(e0), "v"(e1));
            asm("v_cvt_pk_bf16_f32 %0, %1, %2" : "=v"(hi) : "v"(e2), "v"(e3));
            p0[jt] = lo; p1[jt] = hi;
        }
        sum += __shfl_xor(sum, 16);
        sum += __shfl_xor(sum, 32);
        const float inv = 1.0f / sum;
        f32x4 o0 = {0.f, 0.f, 0.f, 0.f}, o1 = {0.f, 0.f, 0.f, 0.f};
        #pragma unroll
        for (int kc = 0; kc < 10; kc++) {
            unsigned int a0q = __shfl(p0[2 * kc], sAg);
            unsigned int b0q = __shfl(p1[2 * kc], sAg);
            unsigned int c0q = __shfl(p0[2 * kc], sBg);
            unsigned int d0q = __shfl(p1[2 * kc], sBg);
            unsigned int a1q = 0, b1q = 0, c1q = 0, d1q = 0;
            if (2 * kc + 1 < TP) {
                a1q = __shfl(p0[2 * kc + 1], sAg);
                b1q = __shfl(p1[2 * kc + 1], sAg);
                c1q = __shfl(p0[2 * kc + 1], sBg);
                d1q = __shfl(p1[2 * kc + 1], sBg);
            }
            u32x4 w;
            w[0] = hiSel ? a1q : a0q;
            w[1] = hiSel ? b1q : b0q;
            w[2] = hiSel ? c1q : c0q;
            w[3] = hiSel ? d1q : d0q;
            s16x8 ap = __builtin_bit_cast(s16x8, w);
            s16x8 b0 = *(const s16x8*)(VtB + vtswz(li,      (kc * 32 + g * 8) * 2));
            s16x8 b1 = *(const s16x8*)(VtB + vtswz(li + 16, (kc * 32 + g * 8) * 2));
            __builtin_amdgcn_s_setprio(1);
            o0 = __builtin_amdgcn_mfma_f32_16x16x32_bf16(ap, b0, o0, 0, 0, 0);
            o1 = __builtin_amdgcn_mfma_f32_16x16x32_bf16(ap, b1, o1, 0, 0, 0);
            __builtin_amdgcn_s_setprio(0);
        }
        #pragma unroll
        for (int r = 0; r < 4; r++) {
            float iv = __shfl(inv, g * 4 + r);
            int i = it * 16 + g * 4 + r;
            if (i < NTOK) {
                size_t ob = ((size_t)bw * NTOK + i) * DIM + h * DH;
                AT[ob + li]      = __float2bfloat16(o0[r] * iv);
                AT[ob + 16 + li] = __float2bfloat16(o1[r] * iv);
            }
        }
    }
}

// ---------- proj MFMA GEMM: EXACT R4 ----------
__global__ __launch_bounds__(256) void proj_mfma(
    const bf16* __restrict__ AT, const unsigned short* __restrict__ Wo,
    float* __restrict__ out) {
    __shared__ unsigned short As[64 * 256];
    __shared__ unsigned short Bs[64 * 256];
    const size_t mBase = (size_t)blockIdx.x * 64;
    stage64_g((const unsigned short*)AT, As, mBase);
    const int tid = threadIdx.x;
    const int wave = tid >> 6, lane = tid & 63;
    const int li = lane & 15, g = lane >> 4;
    const int wm = wave & 1, wn = wave >> 1;
    unsigned int offO[2][4];
    #pragma unroll
    for (int mi = 0; mi < 2; mi++)
        #pragma unroll
        for (int r = 0; r < 4; r++) {
            unsigned int m = (unsigned int)mBase + wm * 32 + mi * 16 + g * 4 + r;
            unsigned int bw = m / 294u, n = m - bw * 294u;
            unsigned int b = bw >> 6, xx = (bw >> 3) & 7u, yy = bw & 7u;
            unsigned int l = n / 49u, rr = n - l * 49u, w1 = rr / 7u, w2 = rr - w1 * 7u;
            offO[mi][r] = ((((((b * 6u + l) * 8u + xx) * 8u + yy) * 7u + w1) * 7u) + w2) * 256u;
        }
    const int koX = (li & 7) * 8;
    for (int ec = 0; ec < 4; ec++) {
        __syncthreads();
        stage64_g(Wo, Bs, (size_t)ec * 64);
        __syncthreads();
        f32x4 acc[2][2];
        #pragma unroll
        for (int mi = 0; mi < 2; mi++)
            #pragma unroll
            for (int ni = 0; ni < 2; ni++) acc[mi][ni] = (f32x4){0.f, 0.f, 0.f, 0.f};
        #pragma unroll
        for (int kc = 0; kc < 8; kc++) {
            const int ko = (kc * 32 + g * 8) ^ koX;
            s16x8 a0 = *(const s16x8*)&As[(wm * 32 + li) * 256 + ko];
            s16x8 a1 = *(const s16x8*)&As[(wm * 32 + 16 + li) * 256 + ko];
            s16x8 b0 = *(const s16x8*)&Bs[(wn * 32 + li) * 256 + ko];
            s16x8 b1 = *(const s16x8*)&Bs[(wn * 32 + 16 + li) * 256 + ko];
            acc[0][0] = __builtin_amdgcn_mfma_f32_16x16x32_bf16(a0, b0, acc[0][0], 0, 0, 0);
            acc[0][1] = __builtin_amdgcn_mfma_f32_16x16x32_bf16(a0, b1, acc[0][1], 0, 0, 0);
            acc[1][0] = __builtin_amdgcn_mfma_f32_16x16x32_bf16(a1, b0, acc[1][0], 0, 0, 0);
            acc[1][1] = __builtin_amdgcn_mfma_f32_16x16x32_bf16(a1, b1, acc[1][1], 0, 0, 0);
        }
        #pragma unroll
        for (int ni = 0; ni < 2; ni++) {
            const unsigned int e = ec * 64 + wn * 32 + ni * 16 + li;
            #pragma unroll
            for (int mi = 0; mi < 2; mi++)
                #pragma unroll
                for (int r = 0; r < 4; r++)
                    __builtin_nontemporal_store(acc[mi][ni][r],
                        &out[(size_t)(offO[mi][r] + e)]);
        }
    }
}

extern "C" void kernel_launch(void* const* d_in, const int* in_sizes, int n_in,
                              void* d_out, int out_size, void* d_ws, size_t ws_size,
                              hipStream_t stream) {
    const long long SZ_X = 9633792, SZ_M = 37632, SZ_WQ = 196608, SZ_WO = 65536, SZ_BT = 14872;
    const void* x = d_in[0]; const void* maskp = d_in[1]; const void* wqkv = d_in[2];
    const void* wout = d_in[3]; const void* btab = d_in[4];
    for (int i = 0; i < n_in; i++) {
        long long s = in_sizes[i];
        if (s == SZ_X) x = d_in[i];
        else if (s == SZ_M) maskp = d_in[i];
        else if (s == SZ_WQ) wqkv = d_in[i];
        else if (s == SZ_WO) wout = d_in[i];
        else if (s == SZ_BT) btab = d_in[i];
    }
    const int* mask = (const int*)maskp;
    float* out = (float*)d_out;
    const size_t SZ = (size_t)BWIN * NTOK * DIM;
    bf16* Q  = (bf16*)d_ws;
    bf16* K  = Q + SZ;
    bf16* V  = K + SZ;
    bf16* AT = V + SZ;
    unsigned short* biasB = (unsigned short*)(AT + SZ);
    const size_t NBB = (size_t)HEADS * TP * TP * 64 * 4;    // bf16 elems
    unsigned short* Wq = biasB + NBB;
    unsigned short* Wo = Wq + 196608;
    prep_kernel<<<dim3(850), dim3(256), 0, stream>>>(
        (const unsigned short*)x, wqkv, wout, btab, Wq, Wo, biasB);
    qkv_mfma<<<dim3(588), dim3(256), 0, stream>>>(x, Wq, Q, K, V);
    attn_mfma<<<dim3(BWIN * HEADS), dim3(512), 0, stream>>>(Q, K, V, biasB, mask, AT);
    proj_mfma<<<dim3(588), dim3(256), 0, stream>>>(AT, Wo, out);
}

// Round 10
// 208.797 us; speedup vs baseline: 1.0626x; 1.0014x over previous
//
#include <hip/hip_runtime.h>
#include <hip/hip_bf16.h>

#define DIM 256
#define HEADS 8
#define DH 32
#define AGENT 6
#define WIN 7
#define NTOK 294              // AGENT*WIN*WIN
#define BWIN 128              // B*X*Y = 2*8*8
#define SCALE 0.17677669529663687f  // 32^-0.5
#define LOG2E 1.4426950408889634f
#define TP 19                 // 16-row tiles covering 294 (padded to 304)
#define QSTR 40               // attn Ks LDS row stride
#define PSTR 320              // attn Vt LDS row stride: 640B = 5*128B (row 128B-aligned)

typedef __hip_bfloat16 bf16;
typedef __attribute__((ext_vector_type(8))) short s16x8;
typedef __attribute__((ext_vector_type(4))) float f32x4;
typedef __attribute__((ext_vector_type(4))) unsigned int u32x4;

#if __has_builtin(__builtin_amdgcn_exp2f)
#define EXP2(x) __builtin_amdgcn_exp2f(x)
#else
#define EXP2(x) exp2f(x)
#endif

__device__ __forceinline__ float bfv(unsigned short u){ return __uint_as_float(((unsigned int)u) << 16); }
__device__ __forceinline__ unsigned short f2bu(float f){
    bf16 b = __float2bfloat16(f); return *reinterpret_cast<unsigned short*>(&b);
}
__device__ __forceinline__ float rdf(const void* p, size_t idx, int isf32) {
    return isf32 ? ((const float*)p)[idx] : bfv(((const unsigned short*)p)[idx]);
}

// Vt byte-address swizzle: row d (128B-aligned, 640B), XOR key permutes 16B slots
// within each 128B block; bijective per row.
__device__ __forceinline__ int vtswz(int d, int cByte) {
    return (d * (PSTR * 2) + cByte) ^ (((d >> 1) & 7) << 4);
}

// async global->LDS, 16B per lane. LDS dest = uniform base + lane*16 (linear).
__device__ __forceinline__ void gll16(const void* gp, void* lp) {
    __builtin_amdgcn_global_load_lds(
        (const __attribute__((address_space(1))) unsigned int*)gp,
        (__attribute__((address_space(3))) unsigned int*)lp, 16, 0, 0);
}

// inline dtype detect: flag=1 -> f32 inputs, flag=0 -> bf16. Pure function of x.
__device__ __forceinline__ int detect_flag(const unsigned short* __restrict__ xraw,
                                           int* sflag, int nthreads) {
    if (threadIdx.x == 0) *sflag = 0;
    __syncthreads();
    int bad = 0;
    for (int i = threadIdx.x; i < 8192; i += nthreads) {
        float v = bfv(xraw[i]);
        if (!(fabsf(v) <= 1e10f)) bad = 1;
    }
    if (bad) atomicOr(sflag, 1);
    __syncthreads();
    return *sflag;
}

// ---------- prep: detect + bias(bf16,LOG2E) + W materialize ----------
// blocks [0,722): biasB ; [722,850): Wq/Wo
__global__ __launch_bounds__(256) void prep_kernel(
    const unsigned short* __restrict__ xraw,
    const void* __restrict__ wq, const void* __restrict__ wo, const void* __restrict__ bt,
    unsigned short* __restrict__ Wq, unsigned short* __restrict__ Wo,
    unsigned short* __restrict__ biasB) {
    __shared__ int sflag;
    const int isf32 = detect_flag(xraw, &sflag, 256);
    const int bid = blockIdx.x;
    if (bid < 722) {
        int idx = bid * 256 + threadIdx.x;
        int lane = idx & 63; int t = idx >> 6;
        int jt = t % TP; t /= TP; int it = t % TP; int h = t / TP;
        int i = it * 16 + (lane & 15);
        int g = lane >> 4;
        ushort4 v;
        unsigned short* vp = (unsigned short*)&v;
        #pragma unroll
        for (int r = 0; r < 4; r++) {
            int j = jt * 16 + g * 4 + r;
            float val = 0.f;
            if (i < NTOK && j < NTOK) {
                int li = i / 49, ri = i - li * 49, w1i = ri / 7, w2i = ri - w1i * 7;
                int lj = j / 49, rj = j - lj * 49, w1j = rj / 7, w2j = rj - w1j * 7;
                int rel = (li - lj + AGENT - 1) * 169 + (w1i - w1j + WIN - 1) * 13 + (w2i - w2j + WIN - 1);
                val = rdf(bt, (size_t)rel * HEADS + h, isf32) * LOG2E;
            }
            vp[r] = f2bu(val);
        }
        ((ushort4*)biasB)[idx] = v;
    } else {
        int c = (bid - 722) * 256 + threadIdx.x;   // chunk of 8 elems
        const void* src; unsigned short* dst; size_t off;
        if (c < 24576) { src = wq; dst = Wq; off = (size_t)c * 8; }
        else           { src = wo; dst = Wo; off = (size_t)(c - 24576) * 8; }
        if (isf32) {
            const float4* s4 = (const float4*)((const float*)src + off);
            float4 v0 = s4[0], v1 = s4[1];
            s16x8 u;
            u[0] = (short)f2bu(v0.x); u[1] = (short)f2bu(v0.y); u[2] = (short)f2bu(v0.z); u[3] = (short)f2bu(v0.w);
            u[4] = (short)f2bu(v1.x); u[5] = (short)f2bu(v1.y); u[6] = (short)f2bu(v1.z); u[7] = (short)f2bu(v1.w);
            *(s16x8*)(dst + off) = u;
        } else {
            *(uint4*)(dst + off) = *(const uint4*)((const unsigned short*)src + off);
        }
    }
}

// stage a 64x256 bf16 tile into LINEAR LDS via global_load_lds, T2 XOR swizzle
// applied on the GLOBAL source address: LDS[row][c'] = G[row][c' ^ (row&7)*8]
__device__ __forceinline__ void stage64_g(const unsigned short* __restrict__ g,
                                          unsigned short* lds, size_t rowBase) {
    const int lane = threadIdx.x & 63, wv = threadIdx.x >> 6;
    const int sub = lane >> 5;
    const int colB = (lane & 31) << 4;
    #pragma unroll
    for (int k = 0; k < 8; k++) {
        const int rr = (wv * 8 + k) * 2 + sub;
        const int cg = colB ^ ((rr & 7) << 4);
        gll16((const char*)g + (rowBase + (size_t)rr) * 512 + cg,
              lds + (size_t)(wv * 8 + k) * 512);
    }
}

// f32 source variant for x: reg-stage + convert + swizzled ds_write, NT loads
__device__ __forceinline__ void stage64_f(const float* __restrict__ g,
                                          unsigned short* lds, size_t rowBase) {
    const int tid = threadIdx.x;
    #pragma unroll
    for (int k = 0; k < 8; k++) {
        int ch = k * 256 + tid;
        int rr = ch >> 5;
        int cB = (ch & 31) << 4;
        int cg = cB ^ ((rr & 7) << 4);
        const f32x4* s4 = (const f32x4*)(g + (rowBase + (size_t)rr) * 256 + (cg >> 1));
        f32x4 v0 = __builtin_nontemporal_load(s4);
        f32x4 v1 = __builtin_nontemporal_load(s4 + 1);
        s16x8 u;
        u[0] = (short)f2bu(v0[0]); u[1] = (short)f2bu(v0[1]); u[2] = (short)f2bu(v0[2]); u[3] = (short)f2bu(v0[3]);
        u[4] = (short)f2bu(v1[0]); u[5] = (short)f2bu(v1[1]); u[6] = (short)f2bu(v1[2]); u[7] = (short)f2bu(v1[3]);
        *(s16x8*)(lds + (size_t)rr * 256 + (cB >> 1)) = u;
    }
}

// ---------- QKV MFMA GEMM (R9, validated): reg-A, aliased dbuf Bs, 1 barrier/chunk ----------
__global__ __launch_bounds__(256) void qkv_mfma(
    const void* __restrict__ xin, const unsigned short* __restrict__ Wq,
    bf16* __restrict__ Q, bf16* __restrict__ K, bf16* __restrict__ V) {
    __shared__ unsigned short P0[64 * 256];    // Bs even chunks
    __shared__ unsigned short P1[64 * 256];    // As (transient), then Bs odd chunks
    __shared__ int sflag;
    const int isf32 = detect_flag((const unsigned short*)xin, &sflag, 256);
    const size_t mBase = (size_t)blockIdx.x * 64;
    if (isf32) stage64_f((const float*)xin, P1, mBase);        // As
    else       stage64_g((const unsigned short*)xin, P1, mBase);
    stage64_g(Wq, P0, 0);                      // Bs chunk 0
    const int tid = threadIdx.x;
    const int wave = tid >> 6, lane = tid & 63;
    const int li = lane & 15, g = lane >> 4;
    const int wm = wave & 1, wn = wave >> 1;
    unsigned int rowOff[2][4];
    #pragma unroll
    for (int mi = 0; mi < 2; mi++)
        #pragma unroll
        for (int r = 0; r < 4; r++) {
            unsigned int m = (unsigned int)mBase + wm * 32 + mi * 16 + g * 4 + r;
            unsigned int w2 = m % 7u, t1 = m / 7u;
            unsigned int w1 = t1 % 7u, t2 = t1 / 7u;
            unsigned int yy = t2 & 7u, t3 = t2 >> 3;
            unsigned int xx = t3 & 7u, t4 = t3 >> 3;
            unsigned int l = t4 % 6u, b = t4 / 6u;
            unsigned int bw = (b << 6) | (xx << 3) | yy;
            unsigned int n = l * 49u + w1 * 7u + w2;
            rowOff[mi][r] = bw * 75264u + n * 32u;   // + h*9408 + d at store
        }
    const int koX = (li & 7) * 8;
    __syncthreads();                           // As + Bs0 resident
    s16x8 a0r[8], a1r[8];
    #pragma unroll
    for (int kc = 0; kc < 8; kc++) {
        const int ko = (kc * 32 + g * 8) ^ koX;
        a0r[kc] = *(const s16x8*)&P1[(wm * 32 + li) * 256 + ko];
        a1r[kc] = *(const s16x8*)&P1[(wm * 32 + 16 + li) * 256 + ko];
    }
    __syncthreads();                           // all A reads done before P1 overwrite
    for (int c = 0; c < 12; c++) {
        const unsigned short* Bc = (c & 1) ? P1 : P0;
        unsigned short* Bn = (c & 1) ? P0 : P1;
        if (c + 1 < 12) stage64_g(Wq, Bn, (size_t)(c + 1) * 64);  // fly during compute
        f32x4 acc[2][2];
        #pragma unroll
        for (int mi = 0; mi < 2; mi++)
            #pragma unroll
            for (int ni = 0; ni < 2; ni++) acc[mi][ni] = (f32x4){0.f, 0.f, 0.f, 0.f};
        #pragma unroll
        for (int kc = 0; kc < 8; kc++) {
            const int ko = (kc * 32 + g * 8) ^ koX;
            s16x8 b0 = *(const s16x8*)&Bc[(wn * 32 + li) * 256 + ko];
            s16x8 b1 = *(const s16x8*)&Bc[(wn * 32 + 16 + li) * 256 + ko];
            acc[0][0] = __builtin_amdgcn_mfma_f32_16x16x32_bf16(a0r[kc], b0, acc[0][0], 0, 0, 0);
            acc[0][1] = __builtin_amdgcn_mfma_f32_16x16x32_bf16(a0r[kc], b1, acc[0][1], 0, 0, 0);
            acc[1][0] = __builtin_amdgcn_mfma_f32_16x16x32_bf16(a1r[kc], b0, acc[1][0], 0, 0, 0);
            acc[1][1] = __builtin_amdgcn_mfma_f32_16x16x32_bf16(a1r[kc], b1, acc[1][1], 0, 0, 0);
        }
        const int p = c >> 2;                  // 0:Q 1:K 2:V
        bf16* dst = (p == 0) ? Q : (p == 1) ? K : V;
        const float sc = (p == 0) ? (SCALE * LOG2E) : 1.0f;
        const unsigned int hoff = ((c & 3) * 2 + wn) * 9408u;
        #pragma unroll
        for (int ni = 0; ni < 2; ni++) {
            const unsigned int d = ni * 16 + li;
            #pragma unroll
            for (int mi = 0; mi < 2; mi++)
                #pragma unroll
                for (int r = 0; r < 4; r++)
                    dst[(size_t)(rowOff[mi][r] + hoff + d)] =
                        __float2bfloat16(acc[mi][ni][r] * sc);
        }
        __syncthreads();                       // drain stage(c+1); WAR for next overwrite
    }
}

// ---------- MFMA attention: R4 core, Q direct-from-global (no Qs LDS) ----------
__global__ __launch_bounds__(512, 2) void attn_mfma(
    const bf16* __restrict__ Q, const bf16* __restrict__ K, const bf16* __restrict__ V,
    const unsigned short* __restrict__ biasB, const int* __restrict__ mask,
    bf16* __restrict__ AT) {
    __shared__ unsigned short Ks[304 * QSTR];
    __shared__ unsigned short Vt[32 * PSTR];
    __shared__ int ms[320];
    const int tid = threadIdx.x;
    const int bw = blockIdx.x >> 3, h = blockIdx.x & 7;
    const size_t base = ((size_t)bw * HEADS + h) * NTOK * DH;
    const unsigned int* Kg = (const unsigned int*)(K + base);
    const unsigned int* Vg = (const unsigned int*)(V + base);
    const unsigned short* Qg = (const unsigned short*)(Q + base);
    char* VtB = (char*)Vt;
    for (int gg = tid; gg < NTOK * DH / 2; gg += 512) {
        int r = gg >> 4, d2 = (gg & 15) * 2;
        unsigned int uk = __builtin_nontemporal_load(&Kg[gg]);
        unsigned int uv = __builtin_nontemporal_load(&Vg[gg]);
        *(unsigned int*)&Ks[r * QSTR + d2] = uk;
        *(unsigned short*)(VtB + vtswz(d2,     r * 2)) = (unsigned short)(uv & 0xffffu);
        *(unsigned short*)(VtB + vtswz(d2 + 1, r * 2)) = (unsigned short)(uv >> 16);
    }
    for (int e = NTOK * QSTR + tid; e < 304 * QSTR; e += 512) { Ks[e] = 0; }
    for (int idx = tid; idx < 32 * (PSTR - NTOK); idx += 512) {
        int d = idx / (PSTR - NTOK), c = NTOK + idx % (PSTR - NTOK);
        *(unsigned short*)(VtB + vtswz(d, c * 2)) = 0;
    }
    for (int j = tid; j < 320; j += 512) {
        int mv = 0;
        if (j < NTOK) { int a = j / 49, jr = j - a * 49; mv = mask[((size_t)bw * 49 + jr) * AGENT + a]; }
        ms[j] = mv;
    }
    __syncthreads();
    const int wave = tid >> 6, lane = tid & 63;
    const int li = lane & 15, g = lane >> 4;
    unsigned int mb0 = 0, mb1 = 0, mb2 = 0;
    for (int jt = 0; jt < TP; jt++)
        for (int r = 0; r < 4; r++) {
            int j = jt * 16 + g * 4 + r;
            if (j < NTOK && ms[j]) {
                int bit = jt * 4 + r;
                if (bit < 32) mb0 |= (1u << bit);
                else if (bit < 64) mb1 |= (1u << (bit - 32));
                else mb2 |= (1u << (bit - 64));
            }
        }
    const ushort4* bb = (const ushort4*)biasB + (size_t)h * TP * TP * 64;
    const int sAg = li + ((lane & 16) << 1);   // li + 32*(g&1)
    const int sBg = sAg + 16;
    const bool hiSel = (lane >= 32);           // g>>1
    for (int it = wave; it < TP; it += 8) {
        // Q direct from global: each wave reads only its own q-rows (16B/lane, L2-hit).
        // Rows >= NTOK read in-workspace garbage; confined to discarded outputs
        // (all cross-lane ops combine same-li lanes; stores guarded by i < NTOK).
        const s16x8 bq = *(const s16x8*)&Qg[((size_t)it * 16 + li) * DH + g * 8];
        f32x4 s[TP];
        __builtin_amdgcn_s_setprio(1);
        #pragma unroll
        for (int jt = 0; jt < TP; jt++) {
            ushort4 bv = bb[(it * TP + jt) * 64 + lane];
            f32x4 c = {bfv(bv.x), bfv(bv.y), bfv(bv.z), bfv(bv.w)};
            s16x8 ak = *(const s16x8*)&Ks[(jt * 16 + li) * QSTR + g * 8];
            s[jt] = __builtin_amdgcn_mfma_f32_16x16x32_bf16(ak, bq, c, 0, 0, 0);
        }
        __builtin_amdgcn_s_setprio(0);
        float mx = -INFINITY;
        #pragma unroll
        for (int jt = 0; jt < TP; jt++)
            #pragma unroll
            for (int r = 0; r < 4; r++) {
                int bit = jt * 4 + r;
                unsigned int w = (bit < 32) ? mb0 : (bit < 64) ? mb1 : mb2;
                float sv = ((w >> (bit & 31)) & 1u) ? s[jt][r] : -1e9f;
                if (jt == TP - 1 && g * 4 + r >= 6) sv = -INFINITY;
                s[jt][r] = sv;
                mx = fmaxf(mx, sv);
            }
        mx = fmaxf(mx, __shfl_xor(mx, 16));
        mx = fmaxf(mx, __shfl_xor(mx, 32));
        float sum = 0.f;
        unsigned int p0[TP], p1[TP];
        #pragma unroll
        for (int jt = 0; jt < TP; jt++) {
            float e0 = EXP2(s[jt][0] - mx);
            float e1 = EXP2(s[jt][1] - mx);
            float e2 = EXP2(s[jt][2] - mx);
            float e3 = EXP2(s[jt][3] - mx);
            sum += (e0 + e1) + (e2 + e3);
            unsigned int lo, hi;
            asm("v_cvt_pk_bf16_f32 %0, %1, %2" : "=v"(lo) : "v"(e0), "v"(e1));
            asm("v_cvt_pk_bf16_f32 %0, %1, %2" : "=v"(hi) : "v"(e2), "v"(e3));
            p0[jt] = lo; p1[jt] = hi;
        }
        sum += __shfl_xor(sum, 16);
        sum += __shfl_xor(sum, 32);
        const float inv = 1.0f / sum;
        f32x4 o0 = {0.f, 0.f, 0.f, 0.f}, o1 = {0.f, 0.f, 0.f, 0.f};
        #pragma unroll
        for (int kc = 0; kc < 10; kc++) {
            unsigned int a0q = __shfl(p0[2 * kc], sAg);
            unsigned int b0q = __shfl(p1[2 * kc], sAg);
            unsigned int c0q = __shfl(p0[2 * kc], sBg);
            unsigned int d0q = __shfl(p1[2 * kc], sBg);
            unsigned int a1q = 0, b1q = 0, c1q = 0, d1q = 0;
            if (2 * kc + 1 < TP) {
                a1q = __shfl(p0[2 * kc + 1], sAg);
                b1q = __shfl(p1[2 * kc + 1], sAg);
                c1q = __shfl(p0[2 * kc + 1], sBg);
                d1q = __shfl(p1[2 * kc + 1], sBg);
            }
            u32x4 w;
            w[0] = hiSel ? a1q : a0q;
            w[1] = hiSel ? b1q : b0q;
            w[2] = hiSel ? c1q : c0q;
            w[3] = hiSel ? d1q : d0q;
            s16x8 ap = __builtin_bit_cast(s16x8, w);
            s16x8 b0 = *(const s16x8*)(VtB + vtswz(li,      (kc * 32 + g * 8) * 2));
            s16x8 b1 = *(const s16x8*)(VtB + vtswz(li + 16, (kc * 32 + g * 8) * 2));
            __builtin_amdgcn_s_setprio(1);
            o0 = __builtin_amdgcn_mfma_f32_16x16x32_bf16(ap, b0, o0, 0, 0, 0);
            o1 = __builtin_amdgcn_mfma_f32_16x16x32_bf16(ap, b1, o1, 0, 0, 0);
            __builtin_amdgcn_s_setprio(0);
        }
        #pragma unroll
        for (int r = 0; r < 4; r++) {
            float iv = __shfl(inv, g * 4 + r);
            int i = it * 16 + g * 4 + r;
            if (i < NTOK) {
                size_t ob = ((size_t)bw * NTOK + i) * DIM + h * DH;
                AT[ob + li]      = __float2bfloat16(o0[r] * iv);
                AT[ob + 16 + li] = __float2bfloat16(o1[r] * iv);
            }
        }
    }
}

// ---------- proj MFMA GEMM: reg-A, aliased dbuf Wo chunks, 1 barrier/chunk ----------
__global__ __launch_bounds__(256) void proj_mfma(
    const bf16* __restrict__ AT, const unsigned short* __restrict__ Wo,
    float* __restrict__ out) {
    __shared__ unsigned short P0[64 * 256];    // Wo even chunks
    __shared__ unsigned short P1[64 * 256];    // As (transient), then Wo odd chunks
    const size_t mBase = (size_t)blockIdx.x * 64;
    stage64_g((const unsigned short*)AT, P1, mBase);   // As
    stage64_g(Wo, P0, 0);                              // chunk 0
    const int tid = threadIdx.x;
    const int wave = tid >> 6, lane = tid & 63;
    const int li = lane & 15, g = lane >> 4;
    const int wm = wave & 1, wn = wave >> 1;
    unsigned int offO[2][4];
    #pragma unroll
    for (int mi = 0; mi < 2; mi++)
        #pragma unroll
        for (int r = 0; r < 4; r++) {
            unsigned int m = (unsigned int)mBase + wm * 32 + mi * 16 + g * 4 + r;
            unsigned int bw = m / 294u, n = m - bw * 294u;
            unsigned int b = bw >> 6, xx = (bw >> 3) & 7u, yy = bw & 7u;
            unsigned int l = n / 49u, rr = n - l * 49u, w1 = rr / 7u, w2 = rr - w1 * 7u;
            offO[mi][r] = ((((((b * 6u + l) * 8u + xx) * 8u + yy) * 7u + w1) * 7u) + w2) * 256u;
        }
    const int koX = (li & 7) * 8;
    __syncthreads();                           // As + chunk0 resident
    s16x8 a0r[8], a1r[8];
    #pragma unroll
    for (int kc = 0; kc < 8; kc++) {
        const int ko = (kc * 32 + g * 8) ^ koX;
        a0r[kc] = *(const s16x8*)&P1[(wm * 32 + li) * 256 + ko];
        a1r[kc] = *(const s16x8*)&P1[(wm * 32 + 16 + li) * 256 + ko];
    }
    __syncthreads();                           // A reads done before P1 overwrite
    for (int ec = 0; ec < 4; ec++) {
        const unsigned short* Bc = (ec & 1) ? P1 : P0;
        unsigned short* Bn = (ec & 1) ? P0 : P1;
        if (ec + 1 < 4) stage64_g(Wo, Bn, (size_t)(ec + 1) * 64);
        f32x4 acc[2][2];
        #pragma unroll
        for (int mi = 0; mi < 2; mi++)
            #pragma unroll
            for (int ni = 0; ni < 2; ni++) acc[mi][ni] = (f32x4){0.f, 0.f, 0.f, 0.f};
        #pragma unroll
        for (int kc = 0; kc < 8; kc++) {
            const int ko = (kc * 32 + g * 8) ^ koX;
            s16x8 b0 = *(const s16x8*)&Bc[(wn * 32 + li) * 256 + ko];
            s16x8 b1 = *(const s16x8*)&Bc[(wn * 32 + 16 + li) * 256 + ko];
            acc[0][0] = __builtin_amdgcn_mfma_f32_16x16x32_bf16(a0r[kc], b0, acc[0][0], 0, 0, 0);
            acc[0][1] = __builtin_amdgcn_mfma_f32_16x16x32_bf16(a0r[kc], b1, acc[0][1], 0, 0, 0);
            acc[1][0] = __builtin_amdgcn_mfma_f32_16x16x32_bf16(a1r[kc], b0, acc[1][0], 0, 0, 0);
            acc[1][1] = __builtin_amdgcn_mfma_f32_16x16x32_bf16(a1r[kc], b1, acc[1][1], 0, 0, 0);
        }
        #pragma unroll
        for (int ni = 0; ni < 2; ni++) {
            const unsigned int e = ec * 64 + wn * 32 + ni * 16 + li;
            #pragma unroll
            for (int mi = 0; mi < 2; mi++)
                #pragma unroll
                for (int r = 0; r < 4; r++)
                    __builtin_nontemporal_store(acc[mi][ni][r],
                        &out[(size_t)(offO[mi][r] + e)]);
        }
        __syncthreads();                       // drain stage(ec+1); WAR protection
    }
}

extern "C" void kernel_launch(void* const* d_in, const int* in_sizes, int n_in,
                              void* d_out, int out_size, void* d_ws, size_t ws_size,
                              hipStream_t stream) {
    const long long SZ_X = 9633792, SZ_M = 37632, SZ_WQ = 196608, SZ_WO = 65536, SZ_BT = 14872;
    const void* x = d_in[0]; const void* maskp = d_in[1]; const void* wqkv = d_in[2];
    const void* wout = d_in[3]; const void* btab = d_in[4];
    for (int i = 0; i < n_in; i++) {
        long long s = in_sizes[i];
        if (s == SZ_X) x = d_in[i];
        else if (s == SZ_M) maskp = d_in[i];
        else if (s == SZ_WQ) wqkv = d_in[i];
        else if (s == SZ_WO) wout = d_in[i];
        else if (s == SZ_BT) btab = d_in[i];
    }
    const int* mask = (const int*)maskp;
    float* out = (float*)d_out;
    const size_t SZ = (size_t)BWIN * NTOK * DIM;
    bf16* Q  = (bf16*)d_ws;
    bf16* K  = Q + SZ;
    bf16* V  = K + SZ;
    bf16* AT = V + SZ;
    unsigned short* biasB = (unsigned short*)(AT + SZ);
    const size_t NBB = (size_t)HEADS * TP * TP * 64 * 4;    // bf16 elems
    unsigned short* Wq = biasB + NBB;
    unsigned short* Wo = Wq + 196608;
    prep_kernel<<<dim3(850), dim3(256), 0, stream>>>(
        (const unsigned short*)x, wqkv, wout, btab, Wq, Wo, biasB);
    qkv_mfma<<<dim3(588), dim3(256), 0, stream>>>(x, Wq, Q, K, V);
    attn_mfma<<<dim3(BWIN * HEADS), dim3(512), 0, stream>>>(Q, K, V, biasB, mask, AT);
    proj_mfma<<<dim3(588), dim3(256), 0, stream>>>(AT, Wo, out);
}